// Round 2
// baseline (201.702 us; speedup 1.0000x reference)
//
#include <hip/hip_runtime.h>
#include <stdint.h>

#define NUM_NODES 17185
#define DD 6
#define FEATS (NUM_NODES * DD)   // 103110
#define BATCH 256
#define EPS 1e-5f

#define NC 256   // nodes per block (== threads, 1 node/thread)
#define BC 16    // batch rows per block
#define NCHUNK ((NUM_NODES + NC - 1) / NC)   // 68
#define ROW_F2 (FEATS / 2)        // 51555 float2 per batch row
#define CHUNK_F2 768              // 256 nodes * 6 floats / 2 per row
#define NIT (BC / 2)              // 8 stage iterations, 2 rows each

// Transposed params, written by prep_kernel each launch (static: no ws-size risk).
// g_W4[c][j4][node] = {w[4j4..4j4+3]} ; g_P4[c][k][node] = {bias[2k],bias[2k+1],a[2k],a[2k+1]}
__device__ float4 g_W4[NCHUNK * 9 * 256];
__device__ float4 g_P4[NCHUNK * 3 * 256];

// LDS swizzle in float2 units: XOR bits [3:1] with bits [6:4].
// Writes (idx = t + 256k): colliding lanes t,t+16,t+32,t+48 get distinct offsets -> conflict-free.
// Reads (idx = 768r + 3t + j): colliding lanes differ by 3 in bits[6:4] -> conflict-free.
__device__ __forceinline__ int sw2(int i) { return i ^ (((i >> 4) & 7) << 1); }

__global__ __launch_bounds__(256) void prep_kernel(
    const float* __restrict__ wb, const float* __restrict__ bb,
    const float* __restrict__ gamma, const float* __restrict__ var,
    const float* __restrict__ fcw, const float* __restrict__ beta,
    const float* __restrict__ mean, float* __restrict__ pc) {
    const int t = threadIdx.x, c = blockIdx.x;
    const int n = c * NC + t;
    const bool valid = (n < NUM_NODES);

    float w[36], bi[6], av[6];
    #pragma unroll
    for (int k = 0; k < 36; k++) w[k] = 0.f;
    #pragma unroll
    for (int k = 0; k < 6; k++) { bi[k] = 0.f; av[k] = 0.f; }
    float cn = 0.f;

    if (valid) {
        const float4* wp = (const float4*)(wb + (size_t)n * 36);
        #pragma unroll
        for (int k = 0; k < 9; k++) {
            float4 v = wp[k];
            w[4*k] = v.x; w[4*k+1] = v.y; w[4*k+2] = v.z; w[4*k+3] = v.w;
        }
        const float2* bp = (const float2*)(bb + (size_t)n * 6);
        #pragma unroll
        for (int k = 0; k < 3; k++) { float2 v = bp[k]; bi[2*k] = v.x; bi[2*k+1] = v.y; }
        const int f0 = n * 6;
        const float2* gp  = (const float2*)(gamma + f0);
        const float2* vp  = (const float2*)(var + f0);
        const float2* fp  = (const float2*)(fcw + f0);
        const float2* bep = (const float2*)(beta + f0);
        const float2* mp  = (const float2*)(mean + f0);
        #pragma unroll
        for (int k = 0; k < 3; k++) {
            float2 g = gp[k], v = vp[k], f = fp[k], be = bep[k], m = mp[k];
            float a0 = g.x * rsqrtf(v.x + EPS) * f.x;
            float a1 = g.y * rsqrtf(v.y + EPS) * f.y;
            av[2*k] = a0; av[2*k+1] = a1;
            cn += be.x * f.x - m.x * a0;
            cn += be.y * f.y - m.y * a1;
        }
    }

    float4* W4 = g_W4 + c * (9 * 256) + t;
    #pragma unroll
    for (int j = 0; j < 9; j++)
        W4[j * 256] = make_float4(w[4*j], w[4*j+1], w[4*j+2], w[4*j+3]);
    float4* P4 = g_P4 + c * (3 * 256) + t;
    #pragma unroll
    for (int k = 0; k < 3; k++)
        P4[k * 256] = make_float4(bi[2*k], bi[2*k+1], av[2*k], av[2*k+1]);

    #pragma unroll
    for (int off = 32; off; off >>= 1) cn += __shfl_down(cn, off);
    __shared__ float credd[4];
    if ((t & 63) == 0) credd[t >> 6] = cn;
    __syncthreads();
    if (t == 0) pc[c] = credd[0] + credd[1] + credd[2] + credd[3];
}

__global__ __launch_bounds__(256) void main_kernel(
    const float* __restrict__ data, float* __restrict__ pm) {
    const int t = threadIdx.x, c = blockIdx.x;
    const int b0 = blockIdx.y * BC;

    // Coalesced param loads (lane-contiguous dwordx4, L2-resident after first y-block).
    float wreg[36], bias[6], a6[6];
    {
        const float4* W4 = g_W4 + c * (9 * 256) + t;
        #pragma unroll
        for (int j = 0; j < 9; j++) {
            float4 v = W4[j * 256];
            wreg[4*j] = v.x; wreg[4*j+1] = v.y; wreg[4*j+2] = v.z; wreg[4*j+3] = v.w;
        }
        const float4* P4 = g_P4 + c * (3 * 256) + t;
        #pragma unroll
        for (int k = 0; k < 3; k++) {
            float4 v = P4[k * 256];
            bias[2*k] = v.x; bias[2*k+1] = v.y; a6[2*k] = v.z; a6[2*k+1] = v.w;
        }
    }

    __shared__ float2 lds2[2 * 1536];   // double-buffered 2-row stage, 24 KB
    const int maxf2 = (c == NCHUNK - 1) ? (ROW_F2 - c * CHUNK_F2) : CHUNK_F2;  // 99 or 768
    const float2* dbase = (const float2*)data + (size_t)c * CHUNK_F2;

    float acc[BC];
    #pragma unroll
    for (int r = 0; r < BC; r++) acc[r] = 0.f;

    float2 st[6];
    // prologue: stage rows {b0, b0+1} into buf 0
    #pragma unroll
    for (int k = 0; k < 6; k++) {
        const int rr = (k >= 3);
        const int off = t + 256 * (k - 3 * rr);
        st[k] = (off < maxf2) ? dbase[(size_t)(b0 + rr) * ROW_F2 + off]
                              : make_float2(0.f, 0.f);
    }
    #pragma unroll
    for (int k = 0; k < 6; k++) {
        const int idx = t + 256 * k;
        lds2[sw2(idx)] = st[k];
    }
    __syncthreads();

    #pragma unroll
    for (int it = 0; it < NIT; ++it) {
        // issue next-stage global loads first (latency hides under compute)
        if (it < NIT - 1) {
            #pragma unroll
            for (int k = 0; k < 6; k++) {
                const int rr = (k >= 3);
                const int off = t + 256 * (k - 3 * rr);
                st[k] = (off < maxf2)
                      ? dbase[(size_t)(b0 + 2 * (it + 1) + rr) * ROW_F2 + off]
                      : make_float2(0.f, 0.f);
            }
        }
        // compute 2 rows from buf (it&1)
        #pragma unroll
        for (int r2 = 0; r2 < 2; r2++) {
            const int base = (it & 1) * 1536 + 768 * r2 + 3 * t;
            float2 u0 = lds2[sw2(base)];
            float2 u1 = lds2[sw2(base + 1)];
            float2 u2 = lds2[sw2(base + 2)];
            float x0 = u0.x, x1 = u0.y, x2 = u1.x, x3 = u1.y, x4 = u2.x, x5 = u2.y;
            #pragma unroll
            for (int o = 0; o < 6; o++) {
                float s = bias[o];
                s = fmaf(x0, wreg[o*6+0], s);
                s = fmaf(x1, wreg[o*6+1], s);
                s = fmaf(x2, wreg[o*6+2], s);
                s = fmaf(x3, wreg[o*6+3], s);
                s = fmaf(x4, wreg[o*6+4], s);
                s = fmaf(x5, wreg[o*6+5], s);
                acc[2*it + r2] = fmaf(fmaxf(s, 0.f), a6[o], acc[2*it + r2]);
            }
        }
        // write next stage to buf ((it+1)&1); implicit vmcnt wait lands here
        if (it < NIT - 1) {
            #pragma unroll
            for (int k = 0; k < 6; k++) {
                const int idx = ((it + 1) & 1) * 1536 + t + 256 * k;
                lds2[sw2(idx)] = st[k];
            }
        }
        __syncthreads();
    }

    // Block reduction: BC independent 6-deep shuffle chains.
    __shared__ float red[4][BC];
    #pragma unroll
    for (int r = 0; r < BC; r++) {
        float v = acc[r];
        #pragma unroll
        for (int off = 32; off; off >>= 1) v += __shfl_down(v, off);
        if ((t & 63) == 0) red[t >> 6][r] = v;
    }
    __syncthreads();
    if (t < BC) {
        float s = red[0][t] + red[1][t] + red[2][t] + red[3][t];
        pm[c * 256 + b0 + t] = s;   // chunk-major for coalesced final read
    }
}

__global__ __launch_bounds__(256) void final_kernel(
    const float* __restrict__ pm, const float* __restrict__ pc,
    const float* __restrict__ fcb, const float* __restrict__ bnfg,
    const float* __restrict__ bnfb, const float* __restrict__ bnfm,
    const float* __restrict__ bnfv, float* __restrict__ out) {
    const int b = threadIdx.x;

    float c = (b < NCHUNK) ? pc[b] : 0.f;
    #pragma unroll
    for (int off = 32; off; off >>= 1) c += __shfl_down(c, off);
    __shared__ float red[4];
    if ((b & 63) == 0) red[b >> 6] = c;
    __syncthreads();
    const float c_sum = red[0] + red[1] + red[2] + red[3];

    float y = 0.f;
    #pragma unroll 4
    for (int ch = 0; ch < NCHUNK; ch++) y += pm[ch * 256 + b];   // coalesced

    y += c_sum + fcb[0];
    float sc = bnfg[0] * rsqrtf(bnfv[0] + EPS);
    float z = (y - bnfm[0]) * sc + bnfb[0];
    out[b] = 1.f / (1.f + expf(-z));
}

extern "C" void kernel_launch(void* const* d_in, const int* in_sizes, int n_in,
                              void* d_out, int out_size, void* d_ws, size_t ws_size,
                              hipStream_t stream) {
    const float* data  = (const float*)d_in[0];
    const float* wb    = (const float*)d_in[1];
    const float* bb    = (const float*)d_in[2];
    const float* gamma = (const float*)d_in[3];
    const float* beta  = (const float*)d_in[4];
    const float* mean  = (const float*)d_in[5];
    const float* var   = (const float*)d_in[6];
    const float* fcw   = (const float*)d_in[7];
    const float* fcb   = (const float*)d_in[8];
    const float* bnfg  = (const float*)d_in[9];
    const float* bnfb  = (const float*)d_in[10];
    const float* bnfm  = (const float*)d_in[11];
    const float* bnfv  = (const float*)d_in[12];

    float* pm = (float*)d_ws;                 // NCHUNK*256 floats
    float* pc = pm + NCHUNK * 256;            // NCHUNK floats

    prep_kernel<<<NCHUNK, 256, 0, stream>>>(wb, bb, gamma, var, fcw, beta, mean, pc);

    dim3 grid(NCHUNK, BATCH / BC);            // (68, 16) = 1088 blocks
    main_kernel<<<grid, NC, 0, stream>>>(data, pm);

    final_kernel<<<1, 256, 0, stream>>>(pm, pc, fcb, bnfg, bnfb, bnfm, bnfv, (float*)d_out);
}